// Round 1
// baseline (515.778 us; speedup 1.0000x reference)
//
#include <hip/hip_runtime.h>
#include <math.h>

// ---------------------------------------------------------------------------
// Segmented softmax: softmax within each contiguous n-best group.
// scores: float32[TOTAL], nBestIndex: int32[NUM_SEG], out: float32[TOTAL].
// Offsets = exclusive prefix sum of nBestIndex (ragged in general).
// ---------------------------------------------------------------------------

// Kernel A: per-block (256-wide) exclusive scan of counts; block totals out.
__global__ __launch_bounds__(256) void scan_local_kernel(
    const int* __restrict__ counts, int n_seg,
    int* __restrict__ local_scan, int* __restrict__ block_sums) {
    __shared__ int sm[256];
    const int t = threadIdx.x;
    const int g = blockIdx.x * 256 + t;
    const int v = (g < n_seg) ? counts[g] : 0;
    sm[t] = v;
    __syncthreads();
    // Hillis-Steele inclusive scan
    for (int off = 1; off < 256; off <<= 1) {
        int y = (t >= off) ? sm[t - off] : 0;
        __syncthreads();
        sm[t] += y;
        __syncthreads();
    }
    if (g < n_seg) local_scan[g] = sm[t] - v;   // exclusive within block
    if (t == 255) block_sums[blockIdx.x] = sm[255];
}

// Kernel B: single-block exclusive scan of block_sums in place (nb <= ~16K).
__global__ __launch_bounds__(256) void scan_bsums_kernel(
    int* __restrict__ bsum, int nb) {
    __shared__ int sm[256];
    const int t = threadIdx.x;
    const int per = (nb + 255) >> 8;
    const int beg = t * per;
    const int end = (beg + per < nb) ? beg + per : nb;
    int tot = 0;
    for (int j = beg; j < end; ++j) tot += bsum[j];
    sm[t] = tot;
    __syncthreads();
    for (int off = 1; off < 256; off <<= 1) {
        int y = (t >= off) ? sm[t - off] : 0;
        __syncthreads();
        sm[t] += y;
        __syncthreads();
    }
    int run = sm[t] - tot;                      // exclusive chunk base
    for (int j = beg; j < end; ++j) {
        int v = bsum[j];
        bsum[j] = run;
        run += v;
    }
}

// Kernel C: one 64-lane wave per segment. Butterfly shuffle reductions.
__global__ __launch_bounds__(256) void seg_softmax_kernel(
    const float* __restrict__ scores, const int* __restrict__ counts,
    const int* __restrict__ local_scan, const int* __restrict__ bsum,
    float* __restrict__ out, int n_seg) {
    const int wave = blockIdx.x * 4 + (threadIdx.x >> 6);
    const int lane = threadIdx.x & 63;
    if (wave >= n_seg) return;

    const int count = counts[wave];
    const int start = local_scan[wave] + bsum[wave >> 8];

    // --- max reduction ---
    float v = -INFINITY;
    if (lane < count) v = scores[start + lane];   // fast path: count <= 64
    float m = v;
    for (int i = lane + 64; i < count; i += 64)
        m = fmaxf(m, scores[start + i]);
    #pragma unroll
    for (int off = 32; off > 0; off >>= 1)
        m = fmaxf(m, __shfl_xor(m, off, 64));

    // --- exp + sum reduction ---
    float e0 = 0.0f, s = 0.0f;
    if (lane < count) { e0 = __expf(v - m); s = e0; }
    for (int i = lane + 64; i < count; i += 64)
        s += __expf(scores[start + i] - m);
    #pragma unroll
    for (int off = 32; off > 0; off >>= 1)
        s += __shfl_xor(s, off, 64);

    const float inv = 1.0f / s;

    // --- write normalized ---
    if (lane < count) out[start + lane] = e0 * inv;
    for (int i = lane + 64; i < count; i += 64)
        out[start + i] = __expf(scores[start + i] - m) * inv;
}

extern "C" void kernel_launch(void* const* d_in, const int* in_sizes, int n_in,
                              void* d_out, int out_size, void* d_ws, size_t ws_size,
                              hipStream_t stream) {
    const float* scores = (const float*)d_in[0];
    const int*   counts = (const int*)d_in[1];
    float* out = (float*)d_out;
    const int n_seg = in_sizes[1];

    // Workspace layout: [n_seg] local exclusive scan | [nblocksA] block sums
    int* local_scan = (int*)d_ws;
    const int nblocksA = (n_seg + 255) / 256;
    int* block_sums = local_scan + n_seg;

    scan_local_kernel<<<nblocksA, 256, 0, stream>>>(counts, n_seg, local_scan, block_sums);
    scan_bsums_kernel<<<1, 256, 0, stream>>>(block_sums, nblocksA);

    const int nblocksC = (n_seg + 3) / 4;   // 4 waves (segments) per block
    seg_softmax_kernel<<<nblocksC, 256, 0, stream>>>(
        scores, counts, local_scan, block_sums, out, n_seg);
}

// Round 2
// 359.456 us; speedup vs baseline: 1.4349x; 1.4349x over previous
//
#include <hip/hip_runtime.h>
#include <math.h>

// ---------------------------------------------------------------------------
// Segmented softmax: softmax within each contiguous n-best group.
// scores: float32[TOTAL], nBestIndex: int32[NUM_SEG], out: float32[TOTAL].
// Offsets = exclusive prefix sum of nBestIndex (ragged in general).
//
// R2 design: block = 256 segments; stage the block's contiguous element span
// into LDS with float4 loads; one thread per segment does the 3-pass softmax
// serially in LDS; float4 stage-out. Kills the VMEM-instruction bottleneck
// of the one-wave-per-segment version (280us @ 1.2 TB/s).
// ---------------------------------------------------------------------------

#define SEGS 256            // segments per block (one thread each in reduce)
#define BLOCK 512           // threads per block (fat stage-in/out)
#define LDS_FLOATS 12928    // 51712 B span buffer -> ~52.7 KB/block -> 3 blocks/CU

// Kernel A: per-block (256-wide) exclusive scan of counts; block totals out.
__global__ __launch_bounds__(256) void scan_local_kernel(
    const int* __restrict__ counts, int n_seg,
    int* __restrict__ local_scan, int* __restrict__ block_sums) {
    __shared__ int sm[256];
    const int t = threadIdx.x;
    const int g = blockIdx.x * 256 + t;
    const int v = (g < n_seg) ? counts[g] : 0;
    sm[t] = v;
    __syncthreads();
    for (int off = 1; off < 256; off <<= 1) {
        int y = (t >= off) ? sm[t - off] : 0;
        __syncthreads();
        sm[t] += y;
        __syncthreads();
    }
    if (g < n_seg) local_scan[g] = sm[t] - v;   // exclusive within block
    if (t == 255) block_sums[blockIdx.x] = sm[255];
}

// Kernel B: single-block exclusive scan of block_sums in place.
__global__ __launch_bounds__(256) void scan_bsums_kernel(
    int* __restrict__ bsum, int nb) {
    __shared__ int sm[256];
    const int t = threadIdx.x;
    const int per = (nb + 255) >> 8;
    const int beg = t * per;
    const int end = (beg + per < nb) ? beg + per : nb;
    int tot = 0;
    for (int j = beg; j < end; ++j) tot += bsum[j];
    sm[t] = tot;
    __syncthreads();
    for (int off = 1; off < 256; off <<= 1) {
        int y = (t >= off) ? sm[t - off] : 0;
        __syncthreads();
        sm[t] += y;
        __syncthreads();
    }
    int run = sm[t] - tot;
    for (int j = beg; j < end; ++j) {
        int v = bsum[j];
        bsum[j] = run;
        run += v;
    }
}

// Kernel C: LDS-staged segmented softmax, 256 segments per block.
__global__ __launch_bounds__(BLOCK) void seg_softmax_kernel(
    const float* __restrict__ scores,
    const int* __restrict__ local_scan, const int* __restrict__ bsum,
    float* __restrict__ out, int n_seg, int total) {
    __shared__ float sm[LDS_FLOATS];
    __shared__ int starts[SEGS + 1];

    const int tid  = threadIdx.x;
    const int seg0 = blockIdx.x * SEGS;

    // Per-segment global start offsets (coalesced 4B loads), +1 for block end.
    if (tid <= SEGS) {
        const int seg = seg0 + tid;
        starts[tid] = (seg < n_seg) ? (local_scan[seg] + bsum[seg >> 8]) : total;
    }
    __syncthreads();

    const int base = starts[0];
    const int span = starts[SEGS] - base;

    if (span <= LDS_FLOATS && (base & 3) == 0) {
        // ---- fast path: stage span into LDS with float4 loads ----
        const float4* __restrict__ src = (const float4*)(scores + base);
        const int nvec = span >> 2;
        for (int i = tid; i < nvec; i += BLOCK)
            ((float4*)sm)[i] = src[i];
        for (int i = (nvec << 2) + tid; i < span; i += BLOCK)
            sm[i] = scores[base + i];
        __syncthreads();

        // ---- one thread per segment: serial 3-pass softmax in LDS ----
        if (tid < SEGS) {
            const int s0 = starts[tid] - base;
            const int c  = starts[tid + 1] - starts[tid];
            if (c > 0) {
                float m = -INFINITY;
                for (int j = 0; j < c; ++j)
                    m = fmaxf(m, sm[s0 + j]);
                float s = 0.0f;
                for (int j = 0; j < c; ++j) {
                    const float e = __expf(sm[s0 + j] - m);
                    sm[s0 + j] = e;
                    s += e;
                }
                const float inv = 1.0f / s;
                for (int j = 0; j < c; ++j)
                    sm[s0 + j] *= inv;
            }
        }
        __syncthreads();

        // ---- stage-out with float4 stores ----
        float4* __restrict__ dst = (float4*)(out + base);
        for (int i = tid; i < nvec; i += BLOCK)
            dst[i] = ((const float4*)sm)[i];
        for (int i = (nvec << 2) + tid; i < span; i += BLOCK)
            out[base + i] = sm[i];
    } else {
        // ---- slow path (span too big for LDS or unaligned): direct global ----
        if (tid < SEGS) {
            const int seg = seg0 + tid;
            if (seg < n_seg) {
                const int st = starts[tid];
                const int c  = starts[tid + 1] - st;
                if (c > 0) {
                    float m = -INFINITY;
                    for (int j = 0; j < c; ++j)
                        m = fmaxf(m, scores[st + j]);
                    float s = 0.0f;
                    for (int j = 0; j < c; ++j)
                        s += __expf(scores[st + j] - m);
                    const float inv = 1.0f / s;
                    for (int j = 0; j < c; ++j)
                        out[st + j] = __expf(scores[st + j] - m) * inv;
                }
            }
        }
    }
}

extern "C" void kernel_launch(void* const* d_in, const int* in_sizes, int n_in,
                              void* d_out, int out_size, void* d_ws, size_t ws_size,
                              hipStream_t stream) {
    const float* scores = (const float*)d_in[0];
    const int*   counts = (const int*)d_in[1];
    float* out = (float*)d_out;
    const int n_seg = in_sizes[1];
    const int total = in_sizes[0];

    // Workspace layout: [n_seg] local exclusive scan | [nblocksA] block sums
    int* local_scan = (int*)d_ws;
    const int nblocksA = (n_seg + 255) / 256;
    int* block_sums = local_scan + n_seg;

    scan_local_kernel<<<nblocksA, 256, 0, stream>>>(counts, n_seg, local_scan, block_sums);
    scan_bsums_kernel<<<1, 256, 0, stream>>>(block_sums, nblocksA);

    const int nblocksC = (n_seg + SEGS - 1) / SEGS;
    seg_softmax_kernel<<<nblocksC, BLOCK, 0, stream>>>(
        scores, local_scan, block_sums, out, n_seg, total);
}